// Round 2
// baseline (574.936 us; speedup 1.0000x reference)
//
#include <hip/hip_runtime.h>
#include <hip/hip_bf16.h>
#include <math.h>

#define BB 2
#define CC 64
#define NN 65536               // pixels per batch (256*256)
#define NPIX (BB*NN)           // 131072

// workspace layout: small fp32 tail first, then bf16 m1
// floats:
#define WS_G    0                      // [B][64][16] = 2048
#define WS_SSQ  2048                   // [2][B][64]  = 256 (0=q,1=k)
#define WS_ATTN 2304                   // [B][64][16] = 2048
#define WS_M1_BYTEOFF ((size_t)4352*4) // bf16 m1: NPIX*CC halves = 16.78 MB

// ---------------------------------------------------------------------------
// K1a: q,k,v projections. Writes v INTO d_out; accumulates Gram G[b,h,d,e]
// and sum-of-squares of q,k per channel via LDS reduce + global atomics.
// ---------------------------------------------------------------------------
__global__ __launch_bounds__(256) void k_qkv(const float* __restrict__ x,
    const float* __restrict__ Wq, const float* __restrict__ Wk,
    const float* __restrict__ Wv, float* __restrict__ ws,
    float* __restrict__ vout)
{
    __shared__ float wt[3*4096];        // [m][c][o] transposed, 48 KB
    __shared__ float s_xq[4][8][128];   // per wave: [j][0..63]=x row, [64..127]=q row
    __shared__ float s_ssq[4][2][64];
    const int tid = threadIdx.x;
    const int lane = tid & 63;
    const int w = tid >> 6;
    const int blk = blockIdx.x;
    const int b = blk >> 8;             // 256 blocks per batch

    for (int i = tid; i < 4096; i += 256) {
        int o = i >> 6, cidx = i & 63;
        wt[cidx*64 + o]        = Wq[i];
        wt[4096 + cidx*64 + o] = Wk[i];
        wt[8192 + cidx*64 + o] = Wv[i];
    }
    __syncthreads();

    float accG[16];
#pragma unroll
    for (int e = 0; e < 16; ++e) accG[e] = 0.f;
    float ssq_q = 0.f, ssq_k = 0.f;
    const int hbase = lane & 48;
    const int pix0 = blk*256 + w*64;

    for (int g = 0; g < 8; ++g) {
        const int pbase = pix0 + g*8;
#pragma unroll
        for (int j = 0; j < 8; ++j)
            s_xq[w][j][lane] = x[(size_t)(pbase+j)*64 + lane];
        __syncthreads();

        float accQ[8], accK[8], accV[8];
#pragma unroll
        for (int j = 0; j < 8; ++j) { accQ[j]=0.f; accK[j]=0.f; accV[j]=0.f; }
        for (int c4 = 0; c4 < 16; ++c4) {
            const int cbase = c4*4;
            float4 x4[8];
#pragma unroll
            for (int j = 0; j < 8; ++j)
                x4[j] = *(const float4*)&s_xq[w][j][cbase];
#pragma unroll
            for (int u = 0; u < 4; ++u) {
                const float wq = wt[(cbase+u)*64 + lane];
                const float wk = wt[4096 + (cbase+u)*64 + lane];
                const float wv = wt[8192 + (cbase+u)*64 + lane];
#pragma unroll
                for (int j = 0; j < 8; ++j) {
                    const float xc = (&x4[j].x)[u];
                    accQ[j] = fmaf(xc, wq, accQ[j]);
                    accK[j] = fmaf(xc, wk, accK[j]);
                    accV[j] = fmaf(xc, wv, accV[j]);
                }
            }
        }
#pragma unroll
        for (int j = 0; j < 8; ++j) {
            vout[(size_t)(pbase+j)*64 + lane] = accV[j];
            s_xq[w][j][64 + lane] = accQ[j];
            ssq_q = fmaf(accQ[j], accQ[j], ssq_q);
            ssq_k = fmaf(accK[j], accK[j], ssq_k);
        }
        __syncthreads();
        // Gram: lane c=h*16+d holds k; read q[h*16+e] broadcast from LDS
#pragma unroll
        for (int j = 0; j < 8; ++j) {
            const float kv = accK[j];
#pragma unroll
            for (int e4 = 0; e4 < 4; ++e4) {
                float4 q4 = *(const float4*)&s_xq[w][j][64 + hbase + e4*4];
                accG[e4*4+0] = fmaf(kv, q4.x, accG[e4*4+0]);
                accG[e4*4+1] = fmaf(kv, q4.y, accG[e4*4+1]);
                accG[e4*4+2] = fmaf(kv, q4.z, accG[e4*4+2]);
                accG[e4*4+3] = fmaf(kv, q4.w, accG[e4*4+3]);
            }
        }
        __syncthreads();
    }

    // cross-wave reduce; reuse s_xq as G_lds[4][1024]
    float* G_lds = &s_xq[0][0][0];
#pragma unroll
    for (int e = 0; e < 16; ++e)
        G_lds[(w*64 + lane)*16 + e] = accG[e];
    s_ssq[w][0][lane] = ssq_q;
    s_ssq[w][1][lane] = ssq_k;
    __syncthreads();
    float* Gg = ws + WS_G + (size_t)b*1024;
    for (int idx = tid; idx < 1024; idx += 256) {
        float s = G_lds[idx] + G_lds[1024+idx] + G_lds[2048+idx] + G_lds[3072+idx];
        atomicAdd(&Gg[idx], s);
    }
    if (tid < 128) {
        int which = tid >> 6, cidx = tid & 63;
        float s = s_ssq[0][which][cidx] + s_ssq[1][which][cidx]
                + s_ssq[2][which][cidx] + s_ssq[3][which][cidx];
        atomicAdd(ws + WS_SSQ + (size_t)which*(BB*64) + b*64 + cidx, s);
    }
}

// ---------------------------------------------------------------------------
// K1b: mask conv1x1: m1 = mask@w1^T + b1, stored as bf16 (0.2% rel err OK).
// ---------------------------------------------------------------------------
__global__ __launch_bounds__(256) void k_mask(const float* __restrict__ mask,
    const float* __restrict__ w1, const float* __restrict__ b1,
    __hip_bfloat16* __restrict__ m1out)
{
    __shared__ float wt[4096];
    __shared__ float s_m[4][8][64];
    const int tid = threadIdx.x, lane = tid & 63, w = tid >> 6;
    const int blk = blockIdx.x;

    for (int i = tid; i < 4096; i += 256) {
        int o = i >> 6, cidx = i & 63;
        wt[cidx*64 + o] = w1[i];
    }
    __syncthreads();
    const float bb1 = b1[lane];
    const int pix0 = blk*256 + w*64;

    for (int g = 0; g < 8; ++g) {
        const int pbase = pix0 + g*8;
#pragma unroll
        for (int j = 0; j < 8; ++j)
            s_m[w][j][lane] = mask[(size_t)(pbase+j)*64 + lane];
        __syncthreads();

        float acc1[8];
#pragma unroll
        for (int j = 0; j < 8; ++j) acc1[j] = bb1;
        for (int c4 = 0; c4 < 16; ++c4) {
            const int cbase = c4*4;
            float4 x4[8];
#pragma unroll
            for (int j = 0; j < 8; ++j) x4[j] = *(const float4*)&s_m[w][j][cbase];
#pragma unroll
            for (int u = 0; u < 4; ++u) {
                const float wv = wt[(cbase+u)*64 + lane];
#pragma unroll
                for (int j = 0; j < 8; ++j)
                    acc1[j] = fmaf((&x4[j].x)[u], wv, acc1[j]);
            }
        }
#pragma unroll
        for (int j = 0; j < 8; ++j)
            m1out[(size_t)(pbase+j)*64 + lane] = __float2bfloat16(acc1[j]);
        __syncthreads();
    }
}

// ---------------------------------------------------------------------------
// K2: attn[b,h,d,e] = softmax_e( G/(||k_d|| ||q_e||) * rescale[h] ). 8 blocks.
// ---------------------------------------------------------------------------
__global__ __launch_bounds__(256) void k_attn(const float* __restrict__ rescale,
                                              float* __restrict__ ws)
{
    const int bh = blockIdx.x;           // b*4+h
    const int b = bh >> 2, h = bh & 3;
    const int t = threadIdx.x;
    const int d = t >> 4, e = t & 15;
    const float* ssq = ws + WS_SSQ;
    float nk = fmaxf(sqrtf(ssq[(size_t)1*(BB*64) + b*64 + h*16 + d]), 1e-12f);
    float nq = fmaxf(sqrtf(ssq[(size_t)0*(BB*64) + b*64 + h*16 + e]), 1e-12f);
    float val = ws[WS_G + (size_t)b*1024 + (h*16+d)*16 + e] / (nk*nq) * rescale[h];
    float m = val;
    for (int off = 1; off < 16; off <<= 1)
        m = fmaxf(m, __shfl_xor(m, off, 16));
    float ev = expf(val - m);
    float s = ev;
    for (int off = 1; off < 16; off <<= 1)
        s += __shfl_xor(s, off, 16);
    ws[WS_ATTN + (size_t)b*1024 + (h*16+d)*16 + e] = ev / s;
}

// ---------------------------------------------------------------------------
// K4: main fusion per 8x8 tile:
//   m1 halo (12x12, bf16->f32, OOB=0) -> m2 = m1@w2^T+b2 (OOB forced 0!) ->
//   dwconv5x5(m2)+dwb -> sigmoid -> ma = m1*(1+sig) -> vm = v(d_out)*ma ->
//   channel attention (attn regs) -> Wp + bp -> WRITE d_out (consumes v
//   in-place; each block only touches its own 64 pixels).
// ---------------------------------------------------------------------------
__global__ __launch_bounds__(256) void k_final(const float* __restrict__ ws,
    const __hip_bfloat16* __restrict__ m1g,
    const float* __restrict__ Wp, const float* __restrict__ bp,
    const float* __restrict__ w2, const float* __restrict__ b2,
    const float* __restrict__ dw, const float* __restrict__ dwb,
    float* __restrict__ out)
{
    __shared__ float m1t[144*64];       // 36 KB  m1 halo (0 outside image)
    __shared__ float m2t[144*64];       // 36 KB  m2 halo (0 outside image)
    __shared__ float w2t[4096];         // 16 KB [c][o]
    __shared__ float wpt[4096];         // 16 KB [c][o]
    __shared__ float s_vm[4][4][64];
    __shared__ float s_out[4][4][64];
    const int tid = threadIdx.x, lane = tid & 63, w = tid >> 6;
    const int bid = blockIdx.x;
    const int b = bid >> 10, tile = bid & 1023;
    const int y0 = (tile >> 5) * 8, x0 = (tile & 31) * 8;
    const int c = lane;
    const int hbase = c & 48;

    // stage m1 halo + weights
    for (int i = tid; i < 9216; i += 256) {       // i&63 == lane
        int yy = i / 768, xx = (i % 768) >> 6;
        int gy = y0 + yy - 2, gx = x0 + xx - 2;
        float v = 0.f;
        if (gy >= 0 && gy < 256 && gx >= 0 && gx < 256)
            v = __bfloat162float(m1g[(((size_t)b*256 + gy)*256 + gx)*64 + c]);
        m1t[i] = v;
    }
    for (int i = tid; i < 4096; i += 256) {
        int o = i >> 6, cidx = i & 63;
        w2t[cidx*64 + o] = w2[i];
        wpt[cidx*64 + o] = Wp[i];
    }
    __syncthreads();

    // m2 halo: wave w computes positions [w*36, (w+1)*36) in 4 chunks of 9
    const float bb2 = b2[lane];
    for (int g2 = 0; g2 < 4; ++g2) {
        const int p0 = w*36 + g2*9;
        float acc[9];
#pragma unroll
        for (int j = 0; j < 9; ++j) acc[j] = bb2;
        for (int c4 = 0; c4 < 16; ++c4) {
            const int cbase = c4*4;
            float4 a4[9];
#pragma unroll
            for (int j = 0; j < 9; ++j)
                a4[j] = *(const float4*)&m1t[(p0+j)*64 + cbase];
#pragma unroll
            for (int u = 0; u < 4; ++u) {
                const float wv = w2t[(cbase+u)*64 + lane];
#pragma unroll
                for (int j = 0; j < 9; ++j)
                    acc[j] = fmaf((&a4[j].x)[u], wv, acc[j]);
            }
        }
#pragma unroll
        for (int j = 0; j < 9; ++j) {
            const int pos = p0 + j;
            const int yy = pos / 12, xx = pos - yy*12;
            const int gy = y0 + yy - 2, gx = x0 + xx - 2;
            const bool ok = (gy >= 0 && gy < 256 && gx >= 0 && gx < 256);
            m2t[pos*64 + lane] = ok ? acc[j] : 0.f;   // conv2 padding is ZERO
        }
    }
    __syncthreads();

    float attn_r[16];
    {
        const float* ag = ws + WS_ATTN + (size_t)b*1024 + c*16;
#pragma unroll
        for (int e = 0; e < 16; ++e) attn_r[e] = ag[e];
    }
    float dwr[25];
#pragma unroll
    for (int k = 0; k < 25; ++k) dwr[k] = dw[c*25+k];
    const float dwbr = dwb[c], bpr = bp[c];

    for (int g = 0; g < 4; ++g) {
#pragma unroll
        for (int j = 0; j < 4; ++j) {
            const int pix = w*16 + g*4 + j;
            const int py = pix >> 3, px = pix & 7;
            const size_t P = (size_t)b*65536 + (size_t)(y0+py)*256 + (x0+px);
            float acc = dwbr;
#pragma unroll
            for (int ky = 0; ky < 5; ++ky)
#pragma unroll
                for (int kx = 0; kx < 5; ++kx)
                    acc = fmaf(m2t[((py+ky)*12 + px+kx)*64 + c], dwr[ky*5+kx], acc);
            const float s = 1.f / (1.f + expf(-acc));
            const float m1v = m1t[((py+2)*12 + (px+2))*64 + c];
            s_vm[w][j][c] = out[P*64 + c] * (m1v * (1.f + s));
        }
        __syncthreads();
#pragma unroll
        for (int j = 0; j < 4; ++j) {
            float o = 0.f;
#pragma unroll
            for (int e4 = 0; e4 < 4; ++e4) {
                float4 v4 = *(const float4*)&s_vm[w][j][hbase + e4*4];
                o = fmaf(attn_r[e4*4+0], v4.x, o);
                o = fmaf(attn_r[e4*4+1], v4.y, o);
                o = fmaf(attn_r[e4*4+2], v4.z, o);
                o = fmaf(attn_r[e4*4+3], v4.w, o);
            }
            s_out[w][j][c] = o;
        }
        __syncthreads();
        float oc[4] = {bpr, bpr, bpr, bpr};
        for (int c4 = 0; c4 < 16; ++c4) {
            const int cbase = c4*4;
            float4 o4[4];
#pragma unroll
            for (int j = 0; j < 4; ++j) o4[j] = *(const float4*)&s_out[w][j][cbase];
#pragma unroll
            for (int u = 0; u < 4; ++u) {
                const float wv = wpt[(cbase+u)*64 + lane];
#pragma unroll
                for (int j = 0; j < 4; ++j)
                    oc[j] = fmaf((&o4[j].x)[u], wv, oc[j]);
            }
        }
#pragma unroll
        for (int j = 0; j < 4; ++j) {
            const int pix = w*16 + g*4 + j;
            const int py = pix >> 3, px = pix & 7;
            const size_t idx = ((size_t)b*65536 + (size_t)(y0+py)*256 + (x0+px))*64 + c;
            out[idx] = oc[j];                     // WRITE (v consumed in-place)
        }
    }
}

// ---------------------------------------------------------------------------
// K3 (runs LAST): positional branch dwconv3x3 -> gelu -> dwconv3x3, += d_out.
// FIX: t1 values at positions outside the image are ZERO (conv2's padding),
// not partial convolutions.
// ---------------------------------------------------------------------------
__global__ __launch_bounds__(256) void k_pe(const float* __restrict__ x,
    const float* __restrict__ w1, const float* __restrict__ w2,
    float* __restrict__ out)
{
    __shared__ float xt[12*12*64];
    __shared__ float t1[10*10*64];
    const int tid = threadIdx.x;
    const int bid = blockIdx.x;
    const int b = bid >> 10, tile = bid & 1023;
    const int y0 = (tile >> 5) * 8, x0 = (tile & 31) * 8;
    const int c = tid & 63;
    float w1r[9], w2r[9];
#pragma unroll
    for (int k = 0; k < 9; ++k) { w1r[k] = w1[c*9+k]; w2r[k] = w2[c*9+k]; }

    for (int i = tid; i < 12*12*64; i += 256) {
        int yy = i / 768, xx = (i % 768) >> 6;
        int gy = y0 + yy - 2, gx = x0 + xx - 2;
        float v = 0.f;
        if (gy >= 0 && gy < 256 && gx >= 0 && gx < 256)
            v = x[(((size_t)b*256 + gy)*256 + gx)*64 + c];
        xt[i] = v;
    }
    __syncthreads();
    for (int i = tid; i < 10*10*64; i += 256) {
        int yy = i / 640, xx = (i % 640) >> 6;
        int gy = y0 + yy - 1, gx = x0 + xx - 1;
        float val = 0.f;
        if (gy >= 0 && gy < 256 && gx >= 0 && gx < 256) {   // FIX: zero outside
            float acc = 0.f;
#pragma unroll
            for (int ky = 0; ky < 3; ++ky)
#pragma unroll
                for (int kx = 0; kx < 3; ++kx)
                    acc = fmaf(xt[((yy+ky)*12 + xx+kx)*64 + c], w1r[ky*3+kx], acc);
            val = 0.5f * acc * (1.f + erff(acc * 0.70710678118654752f));
        }
        t1[i] = val;
    }
    __syncthreads();
    for (int i = tid; i < 8*8*64; i += 256) {
        int yy = i / 512, xx = (i % 512) >> 6;
        float acc = 0.f;
#pragma unroll
        for (int ky = 0; ky < 3; ++ky)
#pragma unroll
            for (int kx = 0; kx < 3; ++kx)
                acc = fmaf(t1[((yy+ky)*10 + xx+kx)*64 + c], w2r[ky*3+kx], acc);
        out[(((size_t)b*256 + y0+yy)*256 + x0+xx)*64 + c] += acc;
    }
}

extern "C" void kernel_launch(void* const* d_in, const int* in_sizes, int n_in,
                              void* d_out, int out_size, void* d_ws, size_t ws_size,
                              hipStream_t stream)
{
    const float* x    = (const float*)d_in[0];
    const float* mask = (const float*)d_in[1];
    const float* Wq   = (const float*)d_in[2];
    const float* Wk   = (const float*)d_in[3];
    const float* Wv   = (const float*)d_in[4];
    const float* resc = (const float*)d_in[5];
    const float* Wp   = (const float*)d_in[6];
    const float* bp   = (const float*)d_in[7];
    const float* mw1  = (const float*)d_in[8];
    const float* mb1  = (const float*)d_in[9];
    const float* mw2  = (const float*)d_in[10];
    const float* mb2  = (const float*)d_in[11];
    const float* mdw  = (const float*)d_in[12];
    const float* mdwb = (const float*)d_in[13];
    const float* pw1  = (const float*)d_in[14];
    const float* pw2  = (const float*)d_in[15];
    float* ws  = (float*)d_ws;
    __hip_bfloat16* m1 = (__hip_bfloat16*)((char*)d_ws + WS_M1_BYTEOFF);
    float* out = (float*)d_out;

    // zero G + ssq accumulators (ws is poisoned 0xAA before each launch)
    hipMemsetAsync(ws, 0, (size_t)2304*sizeof(float), stream);

    k_qkv  <<<512,  256, 0, stream>>>(x, Wq, Wk, Wv, ws, out);   // v -> d_out
    k_mask <<<512,  256, 0, stream>>>(mask, mw1, mb1, m1);
    k_attn <<<8,    256, 0, stream>>>(resc, ws);
    k_final<<<2048, 256, 0, stream>>>(ws, m1, Wp, bp, mw2, mb2, mdw, mdwb, out);
    k_pe   <<<2048, 256, 0, stream>>>(x, pw1, pw2, out);         // += PE, last
}

// Round 3
// 458.493 us; speedup vs baseline: 1.2540x; 1.2540x over previous
//
#include <hip/hip_runtime.h>
#include <hip/hip_bf16.h>
#include <math.h>

#define BB 2
#define NPIX 131072            // 2*256*256

// ws float header
#define WS_G    0              // [B][64][16] = 2048
#define WS_SSQ  2048           // [2][B][64]  = 256 (0=q,1=k)
#define WS_M    2304           // [B][c][o]   = 8192 (folded Wp*blockdiag(attn), transposed)
#define WS_HDR  10496
#define WS_M2_BYTE ((size_t)WS_HDR*4)   // 41984 B (128-aligned); m2 bf16: 16.78 MB

// ---------------------------------------------------------------------------
// K1: fused 5-GEMM per pixel: q,k,v from x; m1,m2 from mask.
//   writes vm0 = v*m1 -> d_out ; m2 -> ws (bf16) ; G + ssq atomics -> ws hdr.
// Per-wave LDS buffers, barrier-free main loop. Weights padded stride 65.
// ---------------------------------------------------------------------------
__global__ __launch_bounds__(256, 1) void k_qkv5(
    const float* __restrict__ x, const float* __restrict__ mask,
    const float* __restrict__ Wq, const float* __restrict__ Wk,
    const float* __restrict__ Wv,
    const float* __restrict__ w1, const float* __restrict__ b1,
    const float* __restrict__ w2, const float* __restrict__ b2,
    float* __restrict__ ws, float* __restrict__ vout,
    __hip_bfloat16* __restrict__ m2out)
{
    __shared__ float wt[5*4160];        // [mat][c*65+o], 83.2 KB, conflict-free
    __shared__ float sbuf[4][2][8][64]; // per-wave: [0]=x->q, [1]=mask->m1
    __shared__ float s_ssq[4][2][64];
    const int tid = threadIdx.x, lane = tid & 63, w = tid >> 6;
    const int blk = blockIdx.x, b = blk >> 8;

    for (int i = tid; i < 4096; i += 256) {
        const int o = i >> 6, c = i & 63, p = c*65 + o;
        wt[p]         = Wq[i];
        wt[4160 + p]  = Wk[i];
        wt[8320 + p]  = Wv[i];
        wt[12480 + p] = w1[i];
        wt[16640 + p] = w2[i];
    }
    __syncthreads();

    float accG[16];
#pragma unroll
    for (int e = 0; e < 16; ++e) accG[e] = 0.f;
    float ssq_q = 0.f, ssq_k = 0.f;
    const float bb1 = b1[lane], bb2 = b2[lane];
    const int hbase = lane & 48;
    const int pix0 = blk*256 + w*64;

    for (int g = 0; g < 8; ++g) {
        const int pbase = pix0 + g*8;
#pragma unroll
        for (int j = 0; j < 8; ++j) {
            sbuf[w][0][j][lane] = x[(size_t)(pbase+j)*64 + lane];
            sbuf[w][1][j][lane] = mask[(size_t)(pbase+j)*64 + lane];
        }
        __builtin_amdgcn_wave_barrier();

        float accQ[8], accK[8], accV[8], accM[8];
#pragma unroll
        for (int j = 0; j < 8; ++j) { accQ[j]=0.f; accK[j]=0.f; accV[j]=0.f; accM[j]=bb1; }
        for (int c4 = 0; c4 < 16; ++c4) {
            const int cbase = c4*4;
            float4 x4[8], mk4[8];
#pragma unroll
            for (int j = 0; j < 8; ++j) {
                x4[j]  = *(const float4*)&sbuf[w][0][j][cbase];
                mk4[j] = *(const float4*)&sbuf[w][1][j][cbase];
            }
#pragma unroll
            for (int u = 0; u < 4; ++u) {
                const int p = (cbase+u)*65 + lane;
                const float wq = wt[p], wk = wt[4160+p], wv = wt[8320+p], wm = wt[12480+p];
#pragma unroll
                for (int j = 0; j < 8; ++j) {
                    const float xc = (&x4[j].x)[u];
                    accQ[j] = fmaf(xc, wq, accQ[j]);
                    accK[j] = fmaf(xc, wk, accK[j]);
                    accV[j] = fmaf(xc, wv, accV[j]);
                    accM[j] = fmaf((&mk4[j].x)[u], wm, accM[j]);
                }
            }
        }
        __builtin_amdgcn_wave_barrier();
        // q -> buf0 (x dead), m1 -> buf1 (mask dead); vm0 out; ssq
#pragma unroll
        for (int j = 0; j < 8; ++j) {
            sbuf[w][0][j][lane] = accQ[j];
            sbuf[w][1][j][lane] = accM[j];
            vout[(size_t)(pbase+j)*64 + lane] = accV[j] * accM[j];
            ssq_q = fmaf(accQ[j], accQ[j], ssq_q);
            ssq_k = fmaf(accK[j], accK[j], ssq_k);
        }
        __builtin_amdgcn_wave_barrier();
        // Gram: lane c=h*16+d holds k; q[h*16+e] broadcast from buf0
#pragma unroll
        for (int j = 0; j < 8; ++j) {
            const float kv = accK[j];
#pragma unroll
            for (int e4 = 0; e4 < 4; ++e4) {
                float4 q4 = *(const float4*)&sbuf[w][0][j][hbase + e4*4];
                accG[e4*4+0] = fmaf(kv, q4.x, accG[e4*4+0]);
                accG[e4*4+1] = fmaf(kv, q4.y, accG[e4*4+1]);
                accG[e4*4+2] = fmaf(kv, q4.z, accG[e4*4+2]);
                accG[e4*4+3] = fmaf(kv, q4.w, accG[e4*4+3]);
            }
        }
        // m2 = m1 @ w2^T + b2 from buf1, -> bf16
        float accC[8];
#pragma unroll
        for (int j = 0; j < 8; ++j) accC[j] = bb2;
        for (int c4 = 0; c4 < 16; ++c4) {
            const int cbase = c4*4;
            float4 a4[8];
#pragma unroll
            for (int j = 0; j < 8; ++j) a4[j] = *(const float4*)&sbuf[w][1][j][cbase];
#pragma unroll
            for (int u = 0; u < 4; ++u) {
                const float wv2 = wt[16640 + (cbase+u)*65 + lane];
#pragma unroll
                for (int j = 0; j < 8; ++j)
                    accC[j] = fmaf((&a4[j].x)[u], wv2, accC[j]);
            }
        }
#pragma unroll
        for (int j = 0; j < 8; ++j)
            m2out[(size_t)(pbase+j)*64 + lane] = __float2bfloat16(accC[j]);
        __builtin_amdgcn_wave_barrier();
    }

    // block reduction: reuse sbuf (each wave owns floats [w*1024,(w+1)*1024))
    float* G_lds = &sbuf[0][0][0][0];
#pragma unroll
    for (int e = 0; e < 16; ++e)
        G_lds[(w*64 + lane)*16 + e] = accG[e];
    s_ssq[w][0][lane] = ssq_q;
    s_ssq[w][1][lane] = ssq_k;
    __syncthreads();
    float* Gg = ws + WS_G + (size_t)b*1024;
    for (int idx = tid; idx < 1024; idx += 256) {
        float s = G_lds[idx] + G_lds[1024+idx] + G_lds[2048+idx] + G_lds[3072+idx];
        atomicAdd(&Gg[idx], s);
    }
    if (tid < 128) {
        const int which = tid >> 6, cidx = tid & 63;
        float s = s_ssq[0][which][cidx] + s_ssq[1][which][cidx]
                + s_ssq[2][which][cidx] + s_ssq[3][which][cidx];
        atomicAdd(ws + WS_SSQ + (size_t)which*(BB*64) + b*64 + cidx, s);
    }
}

// ---------------------------------------------------------------------------
// K2: softmax over normalized Gram, then fold with Wp:
//   Mt[b][c=h*16+e][o] = sum_d Wp[o][h*16+d] * attn[b][h][d][e].  2 blocks.
// ---------------------------------------------------------------------------
__global__ __launch_bounds__(256) void k_attn(const float* __restrict__ rescale,
    const float* __restrict__ Wp, float* __restrict__ ws)
{
    __shared__ float sAtt[1024];        // [h][d][e]
    const int b = blockIdx.x, t = threadIdx.x;
    const int d = t >> 4, e = t & 15;
    const float* ssq = ws + WS_SSQ;
    const float* G = ws + WS_G + (size_t)b*1024;
#pragma unroll
    for (int h = 0; h < 4; ++h) {
        float nk = fmaxf(sqrtf(ssq[BB*64 + b*64 + h*16 + d]), 1e-12f);
        float nq = fmaxf(sqrtf(ssq[b*64 + h*16 + e]), 1e-12f);
        float val = G[(h*16+d)*16 + e] / (nk*nq) * rescale[h];
        float m = val;
        for (int off = 1; off < 16; off <<= 1) m = fmaxf(m, __shfl_xor(m, off, 16));
        float ev = expf(val - m);
        float s = ev;
        for (int off = 1; off < 16; off <<= 1) s += __shfl_xor(s, off, 16);
        sAtt[h*256 + d*16 + e] = ev / s;
    }
    __syncthreads();
    float* Mtb = ws + WS_M + (size_t)b*4096;
    for (int idx = t; idx < 4096; idx += 256) {
        const int c = idx >> 6, o = idx & 63, h = c >> 4, ee = c & 15;
        float acc = 0.f;
#pragma unroll
        for (int d2 = 0; d2 < 16; ++d2)
            acc = fmaf(Wp[o*64 + h*16 + d2], sAtt[h*256 + d2*16 + ee], acc);
        Mtb[c*64 + o] = acc;
    }
}

// ---------------------------------------------------------------------------
// K3: per 8x8 tile: dwconv5x5(m2 bf16 halo)+dwb -> sigmoid ->
//   vm = vm0(d_out)*(1+sig) -> out = Mt . vm + bp.  Barrier-free main loop.
// LDS = 36 + 16 + 4 = 57.3 KB -> 2 blocks/CU.
// ---------------------------------------------------------------------------
__global__ __launch_bounds__(256) void k_final(
    const __hip_bfloat16* __restrict__ m2g, const float* __restrict__ wsM,
    const float* __restrict__ bp, const float* __restrict__ dw,
    const float* __restrict__ dwb, float* __restrict__ out)
{
    __shared__ float m2t[144*64];       // 36 KB halo (0 outside image)
    __shared__ float Mtl[4096];         // 16 KB [c][o] (already transposed)
    __shared__ float s_vm[4][4][64];    // per-wave
    const int tid = threadIdx.x, lane = tid & 63, w = tid >> 6;
    const int bid = blockIdx.x;
    const int b = bid >> 10, tile = bid & 1023;
    const int y0 = (tile >> 5) * 8, x0 = (tile & 31) * 8;
    const int c = lane;

    for (int i = tid; i < 1024; i += 256)
        ((float4*)Mtl)[i] = ((const float4*)(wsM + (size_t)b*4096))[i];
    for (int i2 = tid; i2 < 2304; i2 += 256) {
        const int pos = i2 >> 4, c4 = (i2 & 15) * 4;
        const int yy = pos / 12, xx = pos - yy*12;
        const int gy = y0 + yy - 2, gx = x0 + xx - 2;
        float4 v4 = make_float4(0.f, 0.f, 0.f, 0.f);
        if (gy >= 0 && gy < 256 && gx >= 0 && gx < 256) {
            ushort4 us = *(const ushort4*)&m2g[(((size_t)b*256 + gy)*256 + gx)*64 + c4];
            v4.x = __uint_as_float((unsigned)us.x << 16);
            v4.y = __uint_as_float((unsigned)us.y << 16);
            v4.z = __uint_as_float((unsigned)us.z << 16);
            v4.w = __uint_as_float((unsigned)us.w << 16);
        }
        *(float4*)&m2t[pos*64 + c4] = v4;
    }
    __syncthreads();

    const float dwbr = dwb[c], bpr = bp[c];
    float dwr[25];
#pragma unroll
    for (int k = 0; k < 25; ++k) dwr[k] = dw[c*25+k];

    for (int g = 0; g < 4; ++g) {
        const int p0 = w*16 + g*4;          // 4 consecutive px in one row
        const int py = p0 >> 3, px0 = p0 & 7;
        float acc[4] = {dwbr, dwbr, dwbr, dwbr};
#pragma unroll
        for (int ky = 0; ky < 5; ++ky) {
            const int rbase = ((py+ky)*12 + px0)*64 + c;
#pragma unroll
            for (int kx8 = 0; kx8 < 8; ++kx8) {
                const float tv = m2t[rbase + kx8*64];
#pragma unroll
                for (int j = 0; j < 4; ++j) {
                    const int kk = kx8 - j;
                    if (kk >= 0 && kk < 5)
                        acc[j] = fmaf(tv, dwr[ky*5 + kk], acc[j]);
                }
            }
        }
        size_t P[4];
#pragma unroll
        for (int j = 0; j < 4; ++j) {
            P[j] = (size_t)b*65536 + (size_t)(y0+py)*256 + (x0+px0+j);
            const float s = 1.f / (1.f + expf(-acc[j]));
            s_vm[w][j][c] = out[P[j]*64 + c] * (1.f + s);   // vm0 * (1+sig)
        }
        __builtin_amdgcn_wave_barrier();
        float oc[4] = {bpr, bpr, bpr, bpr};
        for (int c4 = 0; c4 < 16; ++c4) {
            const int cbase = c4*4;
            float4 v4[4];
#pragma unroll
            for (int j = 0; j < 4; ++j) v4[j] = *(const float4*)&s_vm[w][j][cbase];
#pragma unroll
            for (int u = 0; u < 4; ++u) {
                const float mv = Mtl[(cbase+u)*64 + lane];
#pragma unroll
                for (int j = 0; j < 4; ++j)
                    oc[j] = fmaf((&v4[j].x)[u], mv, oc[j]);
            }
        }
#pragma unroll
        for (int j = 0; j < 4; ++j)
            out[P[j]*64 + c] = oc[j];
        __builtin_amdgcn_wave_barrier();
    }
}

// ---------------------------------------------------------------------------
// K4 (last): PE branch dwconv3x3 -> gelu -> dwconv3x3, += d_out.
// t1 outside image is ZERO (conv2 padding semantics).
// ---------------------------------------------------------------------------
__global__ __launch_bounds__(256) void k_pe(const float* __restrict__ x,
    const float* __restrict__ w1, const float* __restrict__ w2,
    float* __restrict__ out)
{
    __shared__ float xt[12*12*64];
    __shared__ float t1[10*10*64];
    const int tid = threadIdx.x;
    const int bid = blockIdx.x;
    const int b = bid >> 10, tile = bid & 1023;
    const int y0 = (tile >> 5) * 8, x0 = (tile & 31) * 8;
    const int c = tid & 63;
    float w1r[9], w2r[9];
#pragma unroll
    for (int k = 0; k < 9; ++k) { w1r[k] = w1[c*9+k]; w2r[k] = w2[c*9+k]; }

    for (int i = tid; i < 12*12*64; i += 256) {
        int yy = i / 768, xx = (i % 768) >> 6;
        int gy = y0 + yy - 2, gx = x0 + xx - 2;
        float v = 0.f;
        if (gy >= 0 && gy < 256 && gx >= 0 && gx < 256)
            v = x[(((size_t)b*256 + gy)*256 + gx)*64 + c];
        xt[i] = v;
    }
    __syncthreads();
    for (int i = tid; i < 10*10*64; i += 256) {
        int yy = i / 640, xx = (i % 640) >> 6;
        int gy = y0 + yy - 1, gx = x0 + xx - 1;
        float val = 0.f;
        if (gy >= 0 && gy < 256 && gx >= 0 && gx < 256) {
            float acc = 0.f;
#pragma unroll
            for (int ky = 0; ky < 3; ++ky)
#pragma unroll
                for (int kx = 0; kx < 3; ++kx)
                    acc = fmaf(xt[((yy+ky)*12 + xx+kx)*64 + c], w1r[ky*3+kx], acc);
            val = 0.5f * acc * (1.f + erff(acc * 0.70710678118654752f));
        }
        t1[i] = val;
    }
    __syncthreads();
    for (int i = tid; i < 8*8*64; i += 256) {
        int yy = i / 512, xx = (i % 512) >> 6;
        float acc = 0.f;
#pragma unroll
        for (int ky = 0; ky < 3; ++ky)
#pragma unroll
            for (int kx = 0; kx < 3; ++kx)
                acc = fmaf(t1[((yy+ky)*10 + xx+kx)*64 + c], w2r[ky*3+kx], acc);
        out[(((size_t)b*256 + y0+yy)*256 + x0+xx)*64 + c] += acc;
    }
}

extern "C" void kernel_launch(void* const* d_in, const int* in_sizes, int n_in,
                              void* d_out, int out_size, void* d_ws, size_t ws_size,
                              hipStream_t stream)
{
    const float* x    = (const float*)d_in[0];
    const float* mask = (const float*)d_in[1];
    const float* Wq   = (const float*)d_in[2];
    const float* Wk   = (const float*)d_in[3];
    const float* Wv   = (const float*)d_in[4];
    const float* resc = (const float*)d_in[5];
    const float* Wp   = (const float*)d_in[6];
    const float* bp   = (const float*)d_in[7];
    const float* mw1  = (const float*)d_in[8];
    const float* mb1  = (const float*)d_in[9];
    const float* mw2  = (const float*)d_in[10];
    const float* mb2  = (const float*)d_in[11];
    const float* mdw  = (const float*)d_in[12];
    const float* mdwb = (const float*)d_in[13];
    const float* pw1  = (const float*)d_in[14];
    const float* pw2  = (const float*)d_in[15];
    float* ws  = (float*)d_ws;
    __hip_bfloat16* m2 = (__hip_bfloat16*)((char*)d_ws + WS_M2_BYTE);
    float* out = (float*)d_out;

    hipMemsetAsync(ws, 0, (size_t)2304*sizeof(float), stream);   // G + ssq

    k_qkv5 <<<512,  256, 0, stream>>>(x, mask, Wq, Wk, Wv, mw1, mb1, mw2, mb2,
                                      ws, out, m2);
    k_attn <<<2,    256, 0, stream>>>(resc, Wp, ws);
    k_final<<<2048, 256, 0, stream>>>(m2, ws + WS_M, bp, mdw, mdwb, out);
    k_pe   <<<2048, 256, 0, stream>>>(x, pw1, pw2, out);
}